// Round 2
// baseline (19205.362 us; speedup 1.0000x reference)
//
#include <hip/hip_runtime.h>
#include <math.h>

// Problem constants (N,T,V,C,S,CI) = (64,128,25,256,3,64)
constexpr int N_ = 64, T_ = 128, V_ = 25, C_ = 256, S_ = 3;
constexpr int J_ = 384;          // 2*S*CI
constexpr int NT_ = N_ * T_;     // 8192
constexpr int VC_ = V_ * C_;     // 6400
constexpr int SC_ = S_ * C_;     // 768

__device__ __forceinline__ float gelu_f(float x) {
  return 0.5f * x * (1.0f + erff(x * 0.70710678118654752440f));
}
__device__ __forceinline__ float elup1(float x) {  // elu(x)+1
  return x > 0.0f ? x + 1.0f : __expf(x);
}
__device__ __forceinline__ float wave_sum(float x) {
#pragma unroll
  for (int off = 1; off < 64; off <<= 1) x += __shfl_xor(x, off, 64);
  return x;
}
// bf16 storage helpers (storage-only; all math fp32)
__device__ __forceinline__ float bf2f(unsigned short u) {
  union { unsigned int i; float f; } v; v.i = ((unsigned int)u) << 16;
  return v.f;
}
__device__ __forceinline__ unsigned short f2bf(float f) {
  union { float f; unsigned int i; } v; v.f = f;
  unsigned int r = v.i + 0x7fffu + ((v.i >> 16) & 1u);  // RNE
  return (unsigned short)(r >> 16);
}
__device__ __forceinline__ float4 ldbf4(const unsigned short* p) {
  ushort4 u = *(const ushort4*)p;
  float4 r;
  r.x = bf2f(u.x); r.y = bf2f(u.y); r.z = bf2f(u.z); r.w = bf2f(u.w);
  return r;
}

// ================= K1: out = bf16(elu(X @ W + b) + 1) ====================
// X (NT,V,C) fp32 @ W (C,384). block = 1 (n,t) tile, 128 thr (2 waves).
__global__ __launch_bounds__(128) void gemm_in_kernel(
    const float* __restrict__ X, const float* __restrict__ W,
    const float* __restrict__ b, unsigned short* __restrict__ out) {
  __shared__ __align__(16) float xs[VC_];
  const int blk = blockIdx.x;
  const int tid = threadIdx.x;
  const float* Xb = X + (size_t)blk * VC_;
  for (int i = tid; i < VC_; i += 128) xs[i] = Xb[i];
  __syncthreads();
  const int lane = tid & 63, wave = tid >> 6;
  const int nr = wave == 0 ? 13 : 12;
  float acc[13][6];
#pragma unroll
  for (int r = 0; r < 13; ++r)
#pragma unroll
    for (int q = 0; q < 6; ++q) acc[r][q] = 0.f;
#pragma unroll 2
  for (int c = 0; c < C_; ++c) {
    float w[6];
#pragma unroll
    for (int q = 0; q < 6; ++q) w[q] = W[c * J_ + lane + 64 * q];
#pragma unroll
    for (int r = 0; r < 13; ++r) {
      int v = wave + 2 * r;
      float xv = xs[(v < V_ ? v : V_ - 1) * C_ + c];
#pragma unroll
      for (int q = 0; q < 6; ++q) acc[r][q] = fmaf(xv, w[q], acc[r][q]);
    }
  }
  float bj[6];
#pragma unroll
  for (int q = 0; q < 6; ++q) bj[q] = b[lane + 64 * q];
  unsigned short* Ob = out + (size_t)blk * (V_ * J_);
#pragma unroll
  for (int r = 0; r < 13; ++r) {
    int v = wave + 2 * r;
    if (r < nr) {
#pragma unroll
      for (int q = 0; q < 6; ++q)
        Ob[v * J_ + lane + 64 * q] = f2bf(elup1(acc[r][q] + bj[q]));
    }
  }
}

// ============ K2: spatial gram A[n,s,v,u] += sum_{t,c} q*k ===============
// QK bf16 (N,T,V,384); q = [c*6+s], k = [c*6+3+s]. block = (n, t-quarter).
__global__ __launch_bounds__(256) void spatial_A_kernel(
    const unsigned short* __restrict__ QK, float* __restrict__ A) {
  __shared__ __align__(16) float qk[V_ * J_];  // 38.4 KB
  const int n = blockIdx.x >> 2, tq = blockIdx.x & 3;
  const int tid = threadIdx.x;
  float acc[3][3];
#pragma unroll
  for (int i = 0; i < 3; ++i)
#pragma unroll
    for (int s = 0; s < 3; ++s) acc[i][s] = 0.f;
  int pv[3], pu[3];
#pragma unroll
  for (int i = 0; i < 3; ++i) {
    int p = tid + 256 * i;
    pv[i] = p / V_;
    pu[i] = p - V_ * pv[i];
  }
  for (int tt = 0; tt < 32; ++tt) {
    int t = tq * 32 + tt;
    const ushort4* src4 =
        (const ushort4*)(QK + (size_t)(n * T_ + t) * (V_ * J_));
    __syncthreads();
    for (int i = tid; i < V_ * J_ / 4; i += 256) {
      ushort4 u = src4[i];
      qk[4 * i + 0] = bf2f(u.x);
      qk[4 * i + 1] = bf2f(u.y);
      qk[4 * i + 2] = bf2f(u.z);
      qk[4 * i + 3] = bf2f(u.w);
    }
    __syncthreads();
#pragma unroll
    for (int i = 0; i < 3; ++i) {
      if (tid + 256 * i < 625) {
        const float* qr = qk + pv[i] * J_;
        const float* kr = qk + pu[i] * J_;
        for (int c = 0; c < 64; ++c) {
          float2 q01 = *(const float2*)(qr + c * 6);
          float q2 = qr[c * 6 + 2];
          float k0 = kr[c * 6 + 3];
          float2 k12 = *(const float2*)(kr + c * 6 + 4);
          acc[i][0] = fmaf(q01.x, k0, acc[i][0]);
          acc[i][1] = fmaf(q01.y, k12.x, acc[i][1]);
          acc[i][2] = fmaf(q2, k12.y, acc[i][2]);
        }
      }
    }
  }
#pragma unroll
  for (int i = 0; i < 3; ++i)
    if (tid + 256 * i < 625) {
#pragma unroll
      for (int s = 0; s < 3; ++s)
        atomicAdd(&A[((n * S_ + s) * V_ + pv[i]) * V_ + pu[i]], acc[i][s]);
    }
}

// ======= K3: A = A / rowsum + att0  (scale-invariant: /(CI*T) dropped) ====
__global__ __launch_bounds__(64) void norm_A_kernel(
    float* __restrict__ A, const float* __restrict__ att0) {
  const int row = blockIdx.x;           // (n*S+s)*V + v
  const int sv = row % (S_ * V_);       // s*V + v
  const int lane = threadIdx.x;
  float val = (lane < V_) ? A[row * V_ + lane] : 0.f;
  float sum = wave_sum(val);
  if (lane < V_) A[row * V_ + lane] = val / sum + att0[sv * V_ + lane];
}

// ====== K4a: y768[nt, v, s, c] = bf16(sum_u A[n,s,v,u] * x[nt,u,c]) ======
__global__ __launch_bounds__(256) void y768_kernel(
    const float* __restrict__ X, const float* __restrict__ A,
    unsigned short* __restrict__ Y768) {
  __shared__ __align__(16) float xs[2 * VC_];      // 51.2 KB
  __shared__ __align__(16) float As[S_ * V_ * 28]; // padded rows
  const int nt0 = blockIdx.x * 2;
  const int n = nt0 >> 7;
  const int tid = threadIdx.x;  // = c
  for (int i = tid; i < 2 * VC_; i += 256)
    xs[i] = X[(size_t)nt0 * VC_ + i];
  const float* Abase = A + n * (S_ * V_ * V_);
  for (int i = tid; i < S_ * V_ * V_; i += 256) {
    int r = i / V_, u = i - r * V_;
    As[r * 28 + u] = Abase[i];
  }
  __syncthreads();
  float xu0[V_], xu1[V_];
#pragma unroll
  for (int u = 0; u < V_; ++u) {
    xu0[u] = xs[u * C_ + tid];
    xu1[u] = xs[VC_ + u * C_ + tid];
  }
  unsigned short* Ob0 = Y768 + (size_t)nt0 * (V_ * SC_);
  unsigned short* Ob1 = Ob0 + (V_ * SC_);
  for (int v = 0; v < V_; ++v) {
#pragma unroll
    for (int s = 0; s < 3; ++s) {
      const float* Ar = As + (s * V_ + v) * 28;
      float a0 = 0.f, a1 = 0.f;
#pragma unroll
      for (int u = 0; u < V_; ++u) {
        float av = Ar[u];
        a0 = fmaf(av, xu0[u], a0);
        a1 = fmaf(av, xu1[u], a1);
      }
      Ob0[(v * S_ + s) * C_ + tid] = f2bf(a0);
      Ob1[(v * S_ + s) * C_ + tid] = f2bf(a1);
    }
  }
}

// == K4b: y2 = gelu(x + ln(gelu(x + ln(y768@Wo+bo)) @ Wf + bf))  ==========
__global__ __launch_bounds__(256) void spatial_out_kernel(
    const unsigned short* __restrict__ Y768, const float* __restrict__ X,
    const float* __restrict__ Wo, const float* __restrict__ bo,
    const float* __restrict__ Wf, const float* __restrict__ bf,
    float* __restrict__ Y2) {
  __shared__ __align__(16) float ws[32 * 256];  // staged W chunk, 32 KB
  __shared__ __align__(16) float g[VC_];        // gelu intermediate, 25.6 KB
  const int blk = blockIdx.x;
  const int tid = threadIdx.x, lane = tid & 63, wave = tid >> 6;
  const int nr = (wave == 0) ? 7 : 6;
  const unsigned short* Yb = Y768 + (size_t)blk * (V_ * SC_);
  const float* Xb = X + (size_t)blk * VC_;
  int vrow[7];
#pragma unroll
  for (int r = 0; r < 7; ++r) {
    int v = wave + 4 * r;
    vrow[r] = v < V_ ? v : V_ - 1;
  }
  float acc[7][4];
#pragma unroll
  for (int r = 0; r < 7; ++r)
#pragma unroll
    for (int q = 0; q < 4; ++q) acc[r][q] = 0.f;
  // GEMM1: k = (s,c), W row = c*3+s
  for (int s = 0; s < S_; ++s) {
    for (int kc = 0; kc < C_; kc += 32) {
      __syncthreads();
      for (int i = tid; i < 32 * 256; i += 256) {
        int row = i >> 8, m = i & 255;
        ws[i] = Wo[((kc + row) * S_ + s) * C_ + m];
      }
      __syncthreads();
      for (int c = 0; c < 32; c += 4) {
        float4 y4[7];
#pragma unroll
        for (int r = 0; r < 7; ++r)
          y4[r] = ldbf4(Yb + vrow[r] * SC_ + s * C_ + kc + c);
#pragma unroll
        for (int i = 0; i < 4; ++i) {
          float w[4];
#pragma unroll
          for (int q = 0; q < 4; ++q) w[q] = ws[(c + i) * C_ + lane + 64 * q];
#pragma unroll
          for (int r = 0; r < 7; ++r) {
            float yv = (i == 0) ? y4[r].x : (i == 1) ? y4[r].y
                       : (i == 2) ? y4[r].z : y4[r].w;
#pragma unroll
            for (int q = 0; q < 4; ++q) acc[r][q] = fmaf(yv, w[q], acc[r][q]);
          }
        }
      }
    }
  }
  float xres[7][4];
#pragma unroll
  for (int r = 0; r < 7; ++r)
#pragma unroll
    for (int q = 0; q < 4; ++q) xres[r][q] = Xb[vrow[r] * C_ + lane + 64 * q];
  float bo4[4];
#pragma unroll
  for (int q = 0; q < 4; ++q) bo4[q] = bo[lane + 64 * q];
#pragma unroll
  for (int r = 0; r < 7; ++r) {
    float vals[4];
#pragma unroll
    for (int q = 0; q < 4; ++q) vals[q] = acc[r][q] + bo4[q];
    float s1 = vals[0] + vals[1] + vals[2] + vals[3];
    float s2 = vals[0]*vals[0] + vals[1]*vals[1] + vals[2]*vals[2] + vals[3]*vals[3];
    s1 = wave_sum(s1); s2 = wave_sum(s2);
    float mu = s1 * (1.0f / C_);
    float rstd = rsqrtf(fmaxf(s2 * (1.0f / C_) - mu * mu, 0.f) + 1e-5f);
    if (r < nr) {
#pragma unroll
      for (int q = 0; q < 4; ++q)
        g[vrow[r] * C_ + lane + 64 * q] =
            gelu_f(xres[r][q] + (vals[q] - mu) * rstd);
    }
  }
  // GEMM2: 256 -> 256 with W_ffs
  float acc2[7][4];
#pragma unroll
  for (int r = 0; r < 7; ++r)
#pragma unroll
    for (int q = 0; q < 4; ++q) acc2[r][q] = 0.f;
  for (int kc = 0; kc < C_; kc += 32) {
    __syncthreads();
    for (int i = tid; i < 32 * 256; i += 256) {
      int row = i >> 8, m = i & 255;
      ws[i] = Wf[(kc + row) * C_ + m];
    }
    __syncthreads();
    for (int c = 0; c < 32; c += 4) {
      float4 g4[7];
#pragma unroll
      for (int r = 0; r < 7; ++r)
        g4[r] = *(const float4*)(g + vrow[r] * C_ + kc + c);
#pragma unroll
      for (int i = 0; i < 4; ++i) {
        float w[4];
#pragma unroll
        for (int q = 0; q < 4; ++q) w[q] = ws[(c + i) * C_ + lane + 64 * q];
#pragma unroll
        for (int r = 0; r < 7; ++r) {
          float gv = (i == 0) ? g4[r].x : (i == 1) ? g4[r].y
                     : (i == 2) ? g4[r].z : g4[r].w;
#pragma unroll
          for (int q = 0; q < 4; ++q) acc2[r][q] = fmaf(gv, w[q], acc2[r][q]);
        }
      }
    }
  }
  float bf4[4];
#pragma unroll
  for (int q = 0; q < 4; ++q) bf4[q] = bf[lane + 64 * q];
  float* Ob = Y2 + (size_t)blk * VC_;
#pragma unroll
  for (int r = 0; r < 7; ++r) {
    float vals[4];
#pragma unroll
    for (int q = 0; q < 4; ++q) vals[q] = acc2[r][q] + bf4[q];
    float s1 = vals[0] + vals[1] + vals[2] + vals[3];
    float s2 = vals[0]*vals[0] + vals[1]*vals[1] + vals[2]*vals[2] + vals[3]*vals[3];
    s1 = wave_sum(s1); s2 = wave_sum(s2);
    float mu = s1 * (1.0f / C_);
    float rstd = rsqrtf(fmaxf(s2 * (1.0f / C_) - mu * mu, 0.f) + 1e-5f);
    if (r < nr) {
#pragma unroll
      for (int q = 0; q < 4; ++q)
        Ob[vrow[r] * C_ + lane + 64 * q] =
            gelu_f(xres[r][q] + (vals[q] - mu) * rstd);
    }
  }
}

// ====== K6: Af[n,s,t,k] = sum_{v,c} q[t]*k[k]  (unnormalized) ============
__global__ __launch_bounds__(256) void temporal_A_kernel(
    const unsigned short* __restrict__ QK, float* __restrict__ A) {
  __shared__ __align__(16) float Qs[32 * 68];
  __shared__ __align__(16) float Ks[128 * 68];
  const int tt = blockIdx.x, s = blockIdx.y, n = blockIdx.z;
  const int tid = threadIdx.x;
  const int kg = tid & 15;   // k = kg + 16*j
  const int tp = tid >> 4;   // rows tp*2, tp*2+1
  float acc[2][8];
#pragma unroll
  for (int r = 0; r < 2; ++r)
#pragma unroll
    for (int j = 0; j < 8; ++j) acc[r][j] = 0.f;
  for (int v = 0; v < V_; ++v) {
    __syncthreads();
    for (int i = tid; i < 128 * 64; i += 256) {
      int k = i >> 6, c = i & 63;
      Ks[k * 68 + c] =
          bf2f(QK[(size_t)((n * T_ + k) * V_ + v) * J_ + c * 6 + 3 + s]);
    }
    for (int i = tid; i < 32 * 64; i += 256) {
      int t = i >> 6, c = i & 63;
      Qs[t * 68 + c] =
          bf2f(QK[(size_t)((n * T_ + tt * 32 + t) * V_ + v) * J_ + c * 6 + s]);
    }
    __syncthreads();
    for (int c = 0; c < 64; c += 4) {
      float4 q0 = *(const float4*)(Qs + (tp * 2 + 0) * 68 + c);
      float4 q1 = *(const float4*)(Qs + (tp * 2 + 1) * 68 + c);
#pragma unroll
      for (int j = 0; j < 8; ++j) {
        float4 kv = *(const float4*)(Ks + (kg + 16 * j) * 68 + c);
        acc[0][j] = fmaf(q0.x, kv.x, fmaf(q0.y, kv.y,
                    fmaf(q0.z, kv.z, fmaf(q0.w, kv.w, acc[0][j]))));
        acc[1][j] = fmaf(q1.x, kv.x, fmaf(q1.y, kv.y,
                    fmaf(q1.z, kv.z, fmaf(q1.w, kv.w, acc[1][j]))));
      }
    }
  }
  float* Ob = A + ((size_t)(n * S_ + s) * T_ + tt * 32) * T_;
#pragma unroll
  for (int r = 0; r < 2; ++r)
#pragma unroll
    for (int j = 0; j < 8; ++j)
      Ob[(tp * 2 + r) * T_ + kg + 16 * j] = acc[r][j];
}

// ====== K6b: mask (tril/triu) + row-normalize Af and Ab ==================
__global__ __launch_bounds__(64) void norm_temporal_kernel(
    float* __restrict__ Af, float* __restrict__ Ab) {
  const int row = blockIdx.x;  // (n*S+s)*T + t
  const int t = row & (T_ - 1);
  const int lane = threadIdx.x;
  float* A = blockIdx.y == 0 ? Af : Ab;
  const bool fw = blockIdx.y == 0;
  float v0 = A[(size_t)row * T_ + lane];
  float v1 = A[(size_t)row * T_ + lane + 64];
  v0 *= fw ? (lane <= t ? 1.f : 0.f) : (lane >= t ? 1.f : 0.f);
  v1 *= fw ? (lane + 64 <= t ? 1.f : 0.f) : (lane + 64 >= t ? 1.f : 0.f);
  float inv = 1.f / wave_sum(v0 + v1);
  A[(size_t)row * T_ + lane] = v0 * inv;
  A[(size_t)row * T_ + lane + 64] = v1 * inv;
}

// ====== K7: Z[n,s,t,vc] = bf16(sum_k A[n,s,t,k] * Y[n,k,vc]) =============
__global__ __launch_bounds__(256) void temporal_z_kernel(
    const float* __restrict__ A, const float* __restrict__ Y,
    unsigned short* __restrict__ Z) {
  __shared__ __align__(16) float As[16 * T_];  // 8 KB
  const int vt = blockIdx.x;
  const int s = blockIdx.y >> 3, tt = blockIdx.y & 7;
  const int n = blockIdx.z;
  const int tid = threadIdx.x;
  const float* Arow = A + ((size_t)(n * S_ + s) * T_ + tt * 16) * T_;
  for (int i = tid; i < 16 * T_; i += 256) As[i] = Arow[i];
  __syncthreads();
  int col[4];
  bool ok[4];
#pragma unroll
  for (int q = 0; q < 4; ++q) {
    col[q] = vt * 1024 + q * 256 + tid;
    ok[q] = col[q] < VC_;
  }
  float acc[16][4];
#pragma unroll
  for (int r = 0; r < 16; ++r)
#pragma unroll
    for (int q = 0; q < 4; ++q) acc[r][q] = 0.f;
  for (int k = 0; k < T_; k += 4) {
    float y[4][4];
#pragma unroll
    for (int kk = 0; kk < 4; ++kk)
#pragma unroll
      for (int q = 0; q < 4; ++q)
        y[kk][q] = ok[q] ? Y[(size_t)(n * T_ + k + kk) * VC_ + col[q]] : 0.f;
#pragma unroll
    for (int r = 0; r < 16; ++r) {
      float4 a4 = *(const float4*)(As + r * T_ + k);
#pragma unroll
      for (int q = 0; q < 4; ++q) {
        acc[r][q] = fmaf(a4.x, y[0][q], acc[r][q]);
        acc[r][q] = fmaf(a4.y, y[1][q], acc[r][q]);
        acc[r][q] = fmaf(a4.z, y[2][q], acc[r][q]);
        acc[r][q] = fmaf(a4.w, y[3][q], acc[r][q]);
      }
    }
  }
#pragma unroll
  for (int r = 0; r < 16; ++r) {
    unsigned short* Zr =
        Z + ((size_t)(n * S_ + s) * T_ + tt * 16 + r) * VC_;
#pragma unroll
    for (int q = 0; q < 4; ++q)
      if (ok[q]) Zr[col[q]] = f2bf(acc[r][q]);
  }
}

// ====== K8: projf = bf16(ln(z768 @ W_outf + b_outf)) =====================
__global__ __launch_bounds__(256) void proj_f_kernel(
    const unsigned short* __restrict__ Z, const float* __restrict__ Wo,
    const float* __restrict__ bo, unsigned short* __restrict__ P) {
  __shared__ __align__(16) float ws[32 * 256];
  const int blk = blockIdx.x;
  const int n = blk >> 7, t = blk & 127;
  const int tid = threadIdx.x, lane = tid & 63, wave = tid >> 6;
  const int nr = (wave == 0) ? 7 : 6;
  int vrow[7];
#pragma unroll
  for (int r = 0; r < 7; ++r) {
    int v = wave + 4 * r;
    vrow[r] = v < V_ ? v : V_ - 1;
  }
  float acc[7][4];
#pragma unroll
  for (int r = 0; r < 7; ++r)
#pragma unroll
    for (int q = 0; q < 4; ++q) acc[r][q] = 0.f;
  for (int s = 0; s < S_; ++s) {
    const unsigned short* Zs = Z + ((size_t)(n * S_ + s) * T_ + t) * VC_;
    for (int kc = 0; kc < C_; kc += 32) {
      __syncthreads();
      for (int i = tid; i < 32 * 256; i += 256) {
        int row = i >> 8, m = i & 255;
        ws[i] = Wo[((kc + row) * S_ + s) * C_ + m];
      }
      __syncthreads();
      for (int c = 0; c < 32; c += 4) {
        float4 z4[7];
#pragma unroll
        for (int r = 0; r < 7; ++r)
          z4[r] = ldbf4(Zs + vrow[r] * C_ + kc + c);
#pragma unroll
        for (int i = 0; i < 4; ++i) {
          float w[4];
#pragma unroll
          for (int q = 0; q < 4; ++q) w[q] = ws[(c + i) * C_ + lane + 64 * q];
#pragma unroll
          for (int r = 0; r < 7; ++r) {
            float zv = (i == 0) ? z4[r].x : (i == 1) ? z4[r].y
                       : (i == 2) ? z4[r].z : z4[r].w;
#pragma unroll
            for (int q = 0; q < 4; ++q) acc[r][q] = fmaf(zv, w[q], acc[r][q]);
          }
        }
      }
    }
  }
  float bo4[4];
#pragma unroll
  for (int q = 0; q < 4; ++q) bo4[q] = bo[lane + 64 * q];
  unsigned short* Ob = P + (size_t)blk * VC_;
#pragma unroll
  for (int r = 0; r < 7; ++r) {
    float vals[4];
#pragma unroll
    for (int q = 0; q < 4; ++q) vals[q] = acc[r][q] + bo4[q];
    float s1 = vals[0] + vals[1] + vals[2] + vals[3];
    float s2 = vals[0]*vals[0] + vals[1]*vals[1] + vals[2]*vals[2] + vals[3]*vals[3];
    s1 = wave_sum(s1); s2 = wave_sum(s2);
    float mu = s1 * (1.0f / C_);
    float rstd = rsqrtf(fmaxf(s2 * (1.0f / C_) - mu * mu, 0.f) + 1e-5f);
    if (r < nr) {
#pragma unroll
      for (int q = 0; q < 4; ++q)
        Ob[vrow[r] * C_ + lane + 64 * q] = f2bf((vals[q] - mu) * rstd);
    }
  }
}

// == K9: zb=ln(Zb768@W_outb+b); z=gelu(y+pf+zb); out=gelu(y+ln(z@W_fft+b)) =
__global__ __launch_bounds__(256) void proj_final_b_kernel(
    const unsigned short* __restrict__ Z, const float* __restrict__ Wo,
    const float* __restrict__ bo, const unsigned short* __restrict__ Pf,
    const float* __restrict__ Y, const float* __restrict__ Wt,
    const float* __restrict__ bt, float* __restrict__ Out) {
  __shared__ __align__(16) float ws[32 * 256];
  __shared__ __align__(16) float zb[VC_];
  const int blk = blockIdx.x;
  const int n = blk >> 7, t = blk & 127;
  const int tid = threadIdx.x, lane = tid & 63, wave = tid >> 6;
  const int nr = (wave == 0) ? 7 : 6;
  int vrow[7];
#pragma unroll
  for (int r = 0; r < 7; ++r) {
    int v = wave + 4 * r;
    vrow[r] = v < V_ ? v : V_ - 1;
  }
  float acc[7][4];
#pragma unroll
  for (int r = 0; r < 7; ++r)
#pragma unroll
    for (int q = 0; q < 4; ++q) acc[r][q] = 0.f;
  for (int s = 0; s < S_; ++s) {
    const unsigned short* Zs = Z + ((size_t)(n * S_ + s) * T_ + t) * VC_;
    for (int kc = 0; kc < C_; kc += 32) {
      __syncthreads();
      for (int i = tid; i < 32 * 256; i += 256) {
        int row = i >> 8, m = i & 255;
        ws[i] = Wo[((kc + row) * S_ + s) * C_ + m];
      }
      __syncthreads();
      for (int c = 0; c < 32; c += 4) {
        float4 z4[7];
#pragma unroll
        for (int r = 0; r < 7; ++r)
          z4[r] = ldbf4(Zs + vrow[r] * C_ + kc + c);
#pragma unroll
        for (int i = 0; i < 4; ++i) {
          float w[4];
#pragma unroll
          for (int q = 0; q < 4; ++q) w[q] = ws[(c + i) * C_ + lane + 64 * q];
#pragma unroll
          for (int r = 0; r < 7; ++r) {
            float zv = (i == 0) ? z4[r].x : (i == 1) ? z4[r].y
                       : (i == 2) ? z4[r].z : z4[r].w;
#pragma unroll
            for (int q = 0; q < 4; ++q) acc[r][q] = fmaf(zv, w[q], acc[r][q]);
          }
        }
      }
    }
  }
  float yres[7][4];
#pragma unroll
  for (int r = 0; r < 7; ++r)
#pragma unroll
    for (int q = 0; q < 4; ++q)
      yres[r][q] = Y[(size_t)blk * VC_ + vrow[r] * C_ + lane + 64 * q];
  float bo4[4];
#pragma unroll
  for (int q = 0; q < 4; ++q) bo4[q] = bo[lane + 64 * q];
#pragma unroll
  for (int r = 0; r < 7; ++r) {
    float vals[4];
#pragma unroll
    for (int q = 0; q < 4; ++q) vals[q] = acc[r][q] + bo4[q];
    float s1 = vals[0] + vals[1] + vals[2] + vals[3];
    float s2 = vals[0]*vals[0] + vals[1]*vals[1] + vals[2]*vals[2] + vals[3]*vals[3];
    s1 = wave_sum(s1); s2 = wave_sum(s2);
    float mu = s1 * (1.0f / C_);
    float rstd = rsqrtf(fmaxf(s2 * (1.0f / C_) - mu * mu, 0.f) + 1e-5f);
    if (r < nr) {
#pragma unroll
      for (int q = 0; q < 4; ++q) {
        float pf = bf2f(Pf[(size_t)blk * VC_ + vrow[r] * C_ + lane + 64 * q]);
        zb[vrow[r] * C_ + lane + 64 * q] =
            gelu_f(yres[r][q] + pf + (vals[q] - mu) * rstd);
      }
    }
  }
  // GEMM2 with W_fft
  float acc2[7][4];
#pragma unroll
  for (int r = 0; r < 7; ++r)
#pragma unroll
    for (int q = 0; q < 4; ++q) acc2[r][q] = 0.f;
  for (int kc = 0; kc < C_; kc += 32) {
    __syncthreads();
    for (int i = tid; i < 32 * 256; i += 256) {
      int row = i >> 8, m = i & 255;
      ws[i] = Wt[(kc + row) * C_ + m];
    }
    __syncthreads();
    for (int c = 0; c < 32; c += 4) {
      float4 g4[7];
#pragma unroll
      for (int r = 0; r < 7; ++r)
        g4[r] = *(const float4*)(zb + vrow[r] * C_ + kc + c);
#pragma unroll
      for (int i = 0; i < 4; ++i) {
        float w[4];
#pragma unroll
        for (int q = 0; q < 4; ++q) w[q] = ws[(c + i) * C_ + lane + 64 * q];
#pragma unroll
        for (int r = 0; r < 7; ++r) {
          float gv = (i == 0) ? g4[r].x : (i == 1) ? g4[r].y
                     : (i == 2) ? g4[r].z : g4[r].w;
#pragma unroll
          for (int q = 0; q < 4; ++q) acc2[r][q] = fmaf(gv, w[q], acc2[r][q]);
        }
      }
    }
  }
  float bt4[4];
#pragma unroll
  for (int q = 0; q < 4; ++q) bt4[q] = bt[lane + 64 * q];
#pragma unroll
  for (int r = 0; r < 7; ++r) {
    float vals[4];
#pragma unroll
    for (int q = 0; q < 4; ++q) vals[q] = acc2[r][q] + bt4[q];
    float s1 = vals[0] + vals[1] + vals[2] + vals[3];
    float s2 = vals[0]*vals[0] + vals[1]*vals[1] + vals[2]*vals[2] + vals[3]*vals[3];
    s1 = wave_sum(s1); s2 = wave_sum(s2);
    float mu = s1 * (1.0f / C_);
    float rstd = rsqrtf(fmaxf(s2 * (1.0f / C_) - mu * mu, 0.f) + 1e-5f);
    if (r < nr) {
#pragma unroll
      for (int q = 0; q < 4; ++q)
        Out[(size_t)blk * VC_ + vrow[r] * C_ + lane + 64 * q] =
            gelu_f(yres[r][q] + (vals[q] - mu) * rstd);
    }
  }
}

extern "C" void kernel_launch(void* const* d_in, const int* in_sizes, int n_in,
                              void* d_out, int out_size, void* d_ws,
                              size_t ws_size, hipStream_t stream) {
  const float* x      = (const float*)d_in[0];
  const float* W_ins  = (const float*)d_in[1];
  const float* b_ins  = (const float*)d_in[2];
  const float* att0   = (const float*)d_in[3];
  const float* W_outs = (const float*)d_in[4];
  const float* b_outs = (const float*)d_in[5];
  const float* W_ffs  = (const float*)d_in[6];
  const float* b_ffs  = (const float*)d_in[7];
  const float* W_inf  = (const float*)d_in[8];
  const float* b_inf  = (const float*)d_in[9];
  const float* W_inb  = (const float*)d_in[10];
  const float* b_inb  = (const float*)d_in[11];
  const float* W_outf = (const float*)d_in[12];
  const float* b_outf = (const float*)d_in[13];
  const float* W_outb = (const float*)d_in[14];
  const float* b_outb = (const float*)d_in[15];
  const float* W_fft  = (const float*)d_in[16];
  const float* b_fft  = (const float*)d_in[17];
  float* out = (float*)d_out;
  char* base = (char*)d_ws;

  // Workspace layout (bytes). Peak = 654,791,424 B = 624.5 MiB.
  // B0 [0, 314572800): bf16 region, serially reused:
  //   QKs(78.6M e) -> y768(157.3M e) -> QKf+QKb -> Zf -> Zb
  unsigned short* B0    = (unsigned short*)base;
  float*          y2    = (float*)(base + 314572800);           // 209.7 MB fp32
  unsigned short* projf = (unsigned short*)(base + 524288000);  // 104.9 MB bf16
  float*          Asp   = (float*)(base + 629145600);           // 0.48 MB
  float*          Af    = (float*)(base + 629625600);           // 12.6 MB
  float*          Ab    = (float*)(base + 642208512);           // 12.6 MB

  unsigned short* QKs  = B0;
  unsigned short* Y768 = B0;
  unsigned short* QKf  = B0;
  unsigned short* QKb  = B0 + 78643200;
  unsigned short* Zbuf = B0;

  // ---- spatial stage ----
  gemm_in_kernel<<<NT_, 128, 0, stream>>>(x, W_ins, b_ins, QKs);
  hipMemsetAsync(Asp, 0, (size_t)N_ * S_ * V_ * V_ * sizeof(float), stream);
  spatial_A_kernel<<<N_ * 4, 256, 0, stream>>>(QKs, Asp);
  norm_A_kernel<<<N_ * S_ * V_, 64, 0, stream>>>(Asp, att0);
  y768_kernel<<<NT_ / 2, 256, 0, stream>>>(x, Asp, Y768);
  spatial_out_kernel<<<NT_, 256, 0, stream>>>(Y768, x, W_outs, b_outs, W_ffs,
                                              b_ffs, y2);
  // ---- temporal stage ----
  gemm_in_kernel<<<NT_, 128, 0, stream>>>(y2, W_inf, b_inf, QKf);
  gemm_in_kernel<<<NT_, 128, 0, stream>>>(y2, W_inb, b_inb, QKb);
  temporal_A_kernel<<<dim3(4, 3, 64), 256, 0, stream>>>(QKf, Af);
  temporal_A_kernel<<<dim3(4, 3, 64), 256, 0, stream>>>(QKb, Ab);
  norm_temporal_kernel<<<dim3(N_ * S_ * T_, 2), 64, 0, stream>>>(Af, Ab);
  // forward: Zf -> projf (Zbuf overlays dead QKf/QKb)
  temporal_z_kernel<<<dim3(7, 24, 64), 256, 0, stream>>>(Af, y2, Zbuf);
  proj_f_kernel<<<NT_, 256, 0, stream>>>(Zbuf, W_outf, b_outf, projf);
  // backward: Zb -> fused projection + final output
  temporal_z_kernel<<<dim3(7, 24, 64), 256, 0, stream>>>(Ab, y2, Zbuf);
  proj_final_b_kernel<<<NT_, 256, 0, stream>>>(Zbuf, W_outb, b_outb, projf, y2,
                                               W_fft, b_fft, out);
}